// Round 3
// baseline (350.873 us; speedup 1.0000x reference)
//
#include <hip/hip_runtime.h>
#include <hip/hip_bf16.h>
#include <float.h>

#define K_CODES 512
#define D_DIM 256
#define HW 4096
#define TILE_N 64
#define CHUNK_K 32
#define NUM_CHUNKS (K_CODES / CHUNK_K) // 16
#define LDS_PAD 8
#define LDS_STRIDE (D_DIM + LDS_PAD)   // 264 bf16 = 528 B (16B-aligned rows, 4-bank rotation)
#define OUT_ELEMS 33554432             // 32*256*64*64

typedef __attribute__((ext_vector_type(8))) short short8;
typedef __attribute__((ext_vector_type(4))) float floatx4;

// ws layout (bytes):
//   [0, 262144)        E bf16 (512*256*2)
//   [262144, 264192)   eSq f32 (512*4)
//   [264192, 272384)   per-block loss partials f32 (2048*4)

__global__ __launch_bounds__(64) void vq_prep(const float* __restrict__ emb,
                                              __hip_bfloat16* __restrict__ e_bf,
                                              float* __restrict__ eSq) {
    const int k = blockIdx.x;
    const int lane = threadIdx.x;
    const float4 f = *reinterpret_cast<const float4*>(emb + (size_t)k * D_DIM + lane * 4);
    union { __hip_bfloat16 h[4]; unsigned long long u; } cv;
    cv.h[0] = __float2bfloat16(f.x);
    cv.h[1] = __float2bfloat16(f.y);
    cv.h[2] = __float2bfloat16(f.z);
    cv.h[3] = __float2bfloat16(f.w);
    *reinterpret_cast<unsigned long long*>(e_bf + (size_t)k * D_DIM + lane * 4) = cv.u;
    float s = f.x * f.x + f.y * f.y + f.z * f.z + f.w * f.w;
    #pragma unroll
    for (int off = 32; off > 0; off >>= 1) s += __shfl_down(s, off, 64);
    if (lane == 0) eSq[k] = s;
}

__global__ __launch_bounds__(256) void vq_main(const float* __restrict__ latents,
                                               const float* __restrict__ emb,
                                               const __hip_bfloat16* __restrict__ e_bf,
                                               const float* __restrict__ eSq,
                                               float* __restrict__ out,
                                               float* __restrict__ partials) {
    __shared__ __hip_bfloat16 Xs[TILE_N][LDS_STRIDE];   // 33792 B
    __shared__ __hip_bfloat16 Es[CHUNK_K][LDS_STRIDE];  // 16896 B
    __shared__ float EsSq[CHUNK_K];
    __shared__ int inds_s[TILE_N];
    __shared__ float red_s[256];

    const int t = threadIdx.x;
    const int bi = blockIdx.x;
    const int b = bi >> 6;                 // 64 hw-tiles per batch image
    const int hw0 = (bi & 63) << 6;
    const int n = t & 63;                  // local vector id
    const int d0 = t >> 6;                 // 0..3

    // ---- stage X tile (f32 -> bf16 LDS), keep f32 in regs for loss/out phase
    float xreg[64];
    const float* lat_base = latents + (size_t)b * D_DIM * HW + hw0 + n;
    #pragma unroll
    for (int it = 0; it < 64; ++it) {
        const int d = d0 + it * 4;
        const float v = lat_base[(size_t)d * HW];   // coalesced over n
        xreg[it] = v;
        Xs[n][d] = __float2bfloat16(v);
    }

    const int wid  = t >> 6;     // wave id 0..3 -> rows wid*16..wid*16+15
    const int lane = t & 63;
    const int lrow = lane & 15;  // A-row / B-col within 16x16 tile
    const int lgrp = lane >> 4;  // 0..3

    float minv[4];
    int   mink[4];
    #pragma unroll
    for (int j = 0; j < 4; ++j) { minv[j] = FLT_MAX; mink[j] = 0; }

    short8 afrag[8];

    for (int kc = 0; kc < NUM_CHUNKS; ++kc) {
        if (kc) __syncthreads();   // protect Es overwrite vs previous compute
        // ---- stage E chunk: 32 codes x 256 d = 8192 bf16; 256 thr x 8 elems x 4 iters
        {
            const __hip_bfloat16* src = e_bf + (size_t)kc * CHUNK_K * D_DIM;
            #pragma unroll
            for (int it = 0; it < 4; ++it) {
                const int flat = it * 2048 + t * 8;
                const int i = flat >> 8;
                const int d = flat & 255;
                short8 v = *reinterpret_cast<const short8*>(src + flat);
                *reinterpret_cast<short8*>(&Es[i][d]) = v;
            }
            if (t < CHUNK_K) EsSq[t] = eSq[kc * CHUNK_K + t];
        }
        __syncthreads();

        if (kc == 0) {
            #pragma unroll
            for (int ds = 0; ds < 8; ++ds)
                afrag[ds] = *reinterpret_cast<const short8*>(&Xs[wid * 16 + lrow][ds * 32 + lgrp * 8]);
        }

        // ---- compute: 2 col-tiles of 16 codes, K-dim 256 in 8 steps of 32
        #pragma unroll
        for (int ct = 0; ct < 2; ++ct) {
            floatx4 acc = {0.f, 0.f, 0.f, 0.f};
            #pragma unroll
            for (int ds = 0; ds < 8; ++ds) {
                short8 bfrag = *reinterpret_cast<const short8*>(&Es[ct * 16 + lrow][ds * 32 + lgrp * 8]);
                acc = __builtin_amdgcn_mfma_f32_16x16x32_bf16(afrag[ds], bfrag, acc, 0, 0, 0);
            }
            const int kcol = kc * CHUNK_K + ct * 16 + lrow;  // B-col = lane&15
            const float es = EsSq[ct * 16 + lrow];
            #pragma unroll
            for (int j = 0; j < 4; ++j) {
                // C/D layout: col = lane&15, row = (lane>>4)*4 + j
                const float dist = es - 2.0f * acc[j];
                if (dist < minv[j]) { minv[j] = dist; mink[j] = kcol; }
            }
        }
    }

    // ---- reduce (min, idx) across the 16 lanes sharing each row group
    #pragma unroll
    for (int j = 0; j < 4; ++j) {
        #pragma unroll
        for (int off = 1; off < 16; off <<= 1) {
            const float ov = __shfl_xor(minv[j], off, 64);
            const int   ok = __shfl_xor(mink[j], off, 64);
            if (ov < minv[j] || (ov == minv[j] && ok < mink[j])) { minv[j] = ov; mink[j] = ok; }
        }
    }
    if (lrow == 0) {
        #pragma unroll
        for (int j = 0; j < 4; ++j)
            inds_s[wid * 16 + lgrp * 4 + j] = mink[j];
    }
    __syncthreads();

    // ---- gather + transpose-write + loss partial (same (n,d) mapping as staging)
    float lsum = 0.f;
    const int myk = inds_s[n];
    const float* qvec = emb + (size_t)myk * D_DIM;
    float* out_base = out + (size_t)b * D_DIM * HW + hw0 + n;
    #pragma unroll
    for (int it = 0; it < 64; ++it) {
        const int d = d0 + it * 4;
        const float q = qvec[d];              // L1/L2-resident gather
        const float diff = q - xreg[it];
        lsum += diff * diff;
        out_base[(size_t)d * HW] = q;         // coalesced over n
    }

    red_s[t] = lsum;
    __syncthreads();
    for (int s = 128; s > 0; s >>= 1) {
        if (t < s) red_s[t] += red_s[t + s];
        __syncthreads();
    }
    if (t == 0) partials[bi] = red_s[0];
}

__global__ __launch_bounds__(256) void vq_final(const float* __restrict__ partials,
                                                float* __restrict__ loss_out) {
    __shared__ float red_s[256];
    float s = 0.f;
    for (int i = threadIdx.x; i < 2048; i += 256) s += partials[i];
    red_s[threadIdx.x] = s;
    __syncthreads();
    for (int k = 128; k > 0; k >>= 1) {
        if (threadIdx.x < k) red_s[threadIdx.x] += red_s[threadIdx.x + k];
        __syncthreads();
    }
    if (threadIdx.x == 0) {
        const float mean = red_s[0] / 33554432.0f;  // B*H*W*D
        loss_out[0] = mean * 0.25f;  // commitment_loss * BETA
        loss_out[1] = mean;          // embedding_loss
    }
}

extern "C" void kernel_launch(void* const* d_in, const int* in_sizes, int n_in,
                              void* d_out, int out_size, void* d_ws, size_t ws_size,
                              hipStream_t stream) {
    const float* latents = (const float*)d_in[0];
    const float* emb     = (const float*)d_in[1];
    float* out = (float*)d_out;
    char*  ws  = (char*)d_ws;

    __hip_bfloat16* e_bf = (__hip_bfloat16*)ws;
    float* eSq      = (float*)(ws + 262144);
    float* partials = (float*)(ws + 264192);
    float* loss_out = out + OUT_ELEMS;   // losses follow the main tensor

    vq_prep<<<K_CODES, 64, 0, stream>>>(emb, e_bf, eSq);
    vq_main<<<2048, 256, 0, stream>>>(latents, emb, e_bf, eSq, out, partials);
    vq_final<<<1, 256, 0, stream>>>(partials, loss_out);
}